// Round 4
// baseline (38.089 us; speedup 1.0000x reference)
//
#include <hip/hip_runtime.h>

#define NB   4
#define C    19
#define HW   (512 * 1024)          // 524288 pixels per n
#define BPN  256                   // blocks per n
#define NBLK (NB * BPN)            // 1024 blocks
#define SLOT BPN                   // 256 partial slots per bin
#define ITER 4                     // float2 groups per thread (8 px/thread)
                                   // coverage: BPN*256*ITER = 262144 pairs = HW/2 per n  ✓
#define NBIN (NB * C)              // 76

// Pass 1: per-pixel softmax^2-sum + argmax, per-block partials.
__global__ __launch_bounds__(256) void msql_pass1(
    const float* __restrict__ pred,
    float2* __restrict__ part)     // [NBIN][SLOT] of (ssum, count)
{
    __shared__ float    s_ssum[C];
    __shared__ unsigned s_cnt[C];
    const int tid = threadIdx.x;
    if (tid < C) { s_ssum[tid] = 0.0f; s_cnt[tid] = 0u; }
    __syncthreads();

    const unsigned b  = blockIdx.x;
    const unsigned n  = b >> 8;                 // block / BPN
    const unsigned lb = b & (BPN - 1u);
    const float* nbase = pred + (size_t)n * ((size_t)C * HW);

#pragma unroll 1
    for (int it = 0; it < ITER; ++it) {
        // pair index within n: this block owns 256*ITER contiguous pairs
        const unsigned p2 = lb * (256u * ITER) + (unsigned)it * 256u + (unsigned)tid;
        const float* base = nbase + (size_t)p2 * 2;

        float2 x[C];                            // 38 payload VGPRs, coalesced 8B/lane
#pragma unroll
        for (int c = 0; c < C; ++c)
            x[c] = *reinterpret_cast<const float2*>(base + (size_t)c * HW);

#pragma unroll
        for (int j = 0; j < 2; ++j) {
            float m  = j ? x[0].y : x[0].x;
            int  arg = 0;
#pragma unroll
            for (int c = 1; c < C; ++c) {
                float v = j ? x[c].y : x[c].x;
                if (v > m) { m = v; arg = c; }  // strict >: first max (jnp.argmax)
            }
            float s1 = 0.0f, s2 = 0.0f;
#pragma unroll
            for (int c = 0; c < C; ++c) {
                float e = __expf((j ? x[c].y : x[c].x) - m);
                s1 += e;
                s2 = fmaf(e, e, s2);
            }
            const float S = s2 / (s1 * s1);     // sum_c softmax_c^2
            atomicAdd(&s_ssum[arg], S);
            atomicAdd(&s_cnt[arg], 1u);
        }
    }

    __syncthreads();
    if (tid < C) {
        // bin = c*NB + n; every (bin, slot) written every call (no ws zeroing needed)
        part[(((unsigned)tid * NB + n) << 8) + lb] =
            make_float2(s_ssum[tid], (float)s_cnt[tid]);  // counts <= 2048: exact fp32
    }
}

// Fused tail: reduce 256 partials per bin, apply class weight, fold to scalar.
__global__ __launch_bounds__(1024) void msql_tail(
    const float2* __restrict__ part,
    float* __restrict__ out)
{
    __shared__ float l_val[NBIN];
    const int t    = threadIdx.x;
    const int w    = t >> 6;                    // wave 0..15
    const int lane = t & 63;

    for (int bin = w; bin < NBIN; bin += 16) {
        const float2* p = part + ((size_t)bin << 8);
        float ss = 0.0f, cc = 0.0f;
#pragma unroll
        for (int i = 0; i < SLOT / 64; ++i) {   // 4 coalesced float2 per lane
            float2 v = p[lane + (i << 6)];
            ss += v.x; cc += v.y;
        }
#pragma unroll
        for (int off = 32; off > 0; off >>= 1) {
            ss += __shfl_down(ss, off, 64);
            cc += __shfl_down(cc, off, 64);
        }
        if (lane == 0) {
            float denom = fmaxf(powf(cc, 0.2f) * powf((float)HW, 0.8f), 1.0f);
            l_val[bin] = ss / denom;
        }
    }
    __syncthreads();
    if (w == 0) {
        float v = l_val[lane];                  // NBIN=76: lanes 0..63 all valid
        if (lane < NBIN - 64) v += l_val[lane + 64];
#pragma unroll
        for (int off = 32; off > 0; off >>= 1)
            v += __shfl_down(v, off, 64);
        if (lane == 0)
            out[0] = -v / (float)NBIN;
    }
}

extern "C" void kernel_launch(void* const* d_in, const int* in_sizes, int n_in,
                              void* d_out, int out_size, void* d_ws, size_t ws_size,
                              hipStream_t stream) {
    const float* pred = (const float*)d_in[0];
    float*  out  = (float*)d_out;
    float2* part = (float2*)d_ws;               // NBIN*SLOT*8 B = 156 KB

    msql_pass1<<<dim3(NBLK), dim3(256), 0, stream>>>(pred, part);
    msql_tail <<<dim3(1),    dim3(1024), 0, stream>>>(part, out);
}